// Round 15
// baseline (261.462 us; speedup 1.0000x reference)
//
#include <hip/hip_runtime.h>

static inline int ceil_div(int a, int b){ return (a+b-1)/b; }
static inline size_t align_up(size_t x, size_t a){ return (x + a - 1) / a * a; }

typedef __bf16 bf16x8 __attribute__((ext_vector_type(8)));
typedef float  f32x4  __attribute__((ext_vector_type(4)));

static __device__ inline unsigned short f2bf(float f){
    unsigned int u = __float_as_uint(f);
    unsigned int lsb = (u >> 16) & 1u;
    u += 0x7FFFu + lsb;
    return (unsigned short)(u >> 16);
}
static __device__ inline float bf2f(unsigned short b){
    return __uint_as_float(((unsigned int)b) << 16);
}
static __device__ inline unsigned int packbf(float a, float b){
    return (unsigned int)f2bf(a) | ((unsigned int)f2bf(b) << 16);
}

// async 16B global->LDS (wave-uniform LDS base + lane*16 layout)
static __device__ inline void gload_lds16(const void* g, void* l) {
    __builtin_amdgcn_global_load_lds(
        (const __attribute__((address_space(1))) unsigned int*)g,
        (__attribute__((address_space(3))) unsigned int*)l, 16, 0, 0);
}

// Merged prologue: zero cnt | build Bt | convert x -> Xb bf16. All independent.
__global__ __launch_bounds__(256)
void pre_kernel(const float* __restrict__ comp, const float* __restrict__ basis,
                const float* __restrict__ root, unsigned short* __restrict__ Bt, int B,
                const float* __restrict__ x, unsigned int* __restrict__ Xb2, int N,
                int* __restrict__ cnt, int NR) {
    int gtid = blockIdx.x*blockDim.x + threadIdx.x;
    int gsz  = gridDim.x*blockDim.x;
    for (int i = gtid; i < NR; i += gsz) cnt[i] = 0;
    for (int idx = gtid; idx < 128*1152; idx += gsz) {
        int o = idx / 1152, kk = idx - o*1152;
        float val;
        if (kk < 1024) {
            int r = kk >> 7, i = kk & 127;
            val = 0.f;
            for (int b = 0; b < B; ++b)
                val += comp[r*B+b] * basis[((size_t)b*128 + i)*128 + o];
        } else {
            val = root[(size_t)(kk-1024)*128 + o];
        }
        Bt[idx] = f2bf(val);
    }
    for (int tt = gtid; tt < N*64; tt += gsz) {
        int n = tt >> 6, l = tt & 63;
        float2 v = reinterpret_cast<const float2*>(x + (size_t)n*128)[l];
        Xb2[(size_t)n*64 + l] = packbf(v.x, v.y);
    }
}

__global__ void count_kernel(const int* __restrict__ dst, const int* __restrict__ et,
                             int* __restrict__ cnt, int E, int R) {
    int e = blockIdx.x*blockDim.x + threadIdx.x;
    if (e >= E) return;
    atomicAdd(&cnt[(size_t)dst[e]*R + et[e]], 1);
}

// Scan over cnt -> offsets; also seeds binfo[i] = {cnt,0,0,0} when binfo != null.
__global__ __launch_bounds__(256)
void scan_block_kernel(const int* __restrict__ in, int* __restrict__ out,
                       int* __restrict__ bsums, int4* __restrict__ binfo, int n) {
    __shared__ int tsum[256];
    int t = threadIdx.x;
    int idx0 = blockIdx.x*1024 + t*4;
    int v0 = (idx0+0 < n) ? in[idx0+0] : 0;
    int v1 = (idx0+1 < n) ? in[idx0+1] : 0;
    int v2 = (idx0+2 < n) ? in[idx0+2] : 0;
    int v3 = (idx0+3 < n) ? in[idx0+3] : 0;
    if (binfo) {
        if (idx0+0 < n) binfo[idx0+0] = make_int4(v0,0,0,0);
        if (idx0+1 < n) binfo[idx0+1] = make_int4(v1,0,0,0);
        if (idx0+2 < n) binfo[idx0+2] = make_int4(v2,0,0,0);
        if (idx0+3 < n) binfo[idx0+3] = make_int4(v3,0,0,0);
    }
    int s = v0+v1+v2+v3;
    tsum[t] = s; __syncthreads();
    for (int off = 1; off < 256; off <<= 1) {
        int x = (t >= off) ? tsum[t-off] : 0;
        __syncthreads();
        tsum[t] += x;
        __syncthreads();
    }
    int run = tsum[t] - s;
    if (idx0+0 < n) out[idx0+0] = run; run += v0;
    if (idx0+1 < n) out[idx0+1] = run; run += v1;
    if (idx0+2 < n) out[idx0+2] = run; run += v2;
    if (idx0+3 < n) out[idx0+3] = run;
    if (bsums && t == 255) bsums[blockIdx.x] = tsum[255];
}

__global__ void scan_add_kernel(int* __restrict__ out, const int* __restrict__ bs,
                                int n, int total) {
    int i = blockIdx.x*blockDim.x + threadIdx.x;
    if (i < n) out[i] += bs[i >> 10];
    if (i == 0) out[n] = total;
}

// slot = atomicAdd(&offsets[bin],1): offsets mutates into shifted-by-one bounds.
// rank = cnt - atomicSub(&cnt[bin],1): first 3 edges (race order) also recorded in
// binfo[bin].{y,z,w}. slot_off stores PRE-SHIFTED u32 index (src<<6); 4-zero pad.
__global__ void fill_kernel(const int* __restrict__ src, const int* __restrict__ dst,
                            const int* __restrict__ et, int* __restrict__ offsets,
                            int* __restrict__ cnt, int4* __restrict__ binfo,
                            int* __restrict__ slot_off, int E, int R) {
    int e = blockIdx.x*blockDim.x + threadIdx.x;
    if (e >= E) return;
    if (e < 4) slot_off[E + e] = 0;
    int bin = dst[e]*R + et[e];
    int soff = src[e] << 6;
    int slot = atomicAdd(&offsets[bin], 1);
    slot_off[slot] = soff;
    int rank_rev = atomicSub(&cnt[bin], 1);       // cnt .. 1
    int rank = binfo[bin].x - rank_rev;           // 0 .. cnt-1 (binfo.x = original cnt)
    if (rank < 3) ((int*)&binfo[bin])[1 + rank] = soff;
}

// 4 waves per node, 2 bins per wave.
// Fast path (cnt<=3, ~93% of bins incl. empty): ONE int4 binfo load -> <=3 row loads.
// Slow path (cnt>=4): CSR masked-4 loop over [off[b-1], off[b]).
__global__ __launch_bounds__(256)
void aggregate_kernel(const int* __restrict__ offsets, const int* __restrict__ slot_off,
                      const int4* __restrict__ binfo,
                      const unsigned int* __restrict__ Xb2, unsigned int* __restrict__ Mc2,
                      int N) {
    int gw = (int)((blockIdx.x*blockDim.x + threadIdx.x) >> 6);
    int node = gw >> 2, part = gw & 3;
    if (node >= N) return;
    int l = threadIdx.x & 63;
    int base = node*8 + part*2;

    unsigned int res[2];

    #pragma unroll
    for (int bb = 0; bb < 2; ++bb) {
        int bin = base + bb;
        int4 bi = binfo[bin];
        int cnt = bi.x;
        float ax, ay;
        if (cnt <= 3) {
            // masked 3-wide: unwritten binfo slots are 0 (valid addr), zero-masked.
            unsigned int u0 = Xb2[(unsigned)(bi.y + l)];
            unsigned int u1 = Xb2[(unsigned)(bi.z + l)];
            unsigned int u2 = Xb2[(unsigned)(bi.w + l)];
            if (cnt < 1) u0 = 0u;
            if (cnt < 2) u1 = 0u;
            if (cnt < 3) u2 = 0u;
            ax = __uint_as_float(u0 << 16) + __uint_as_float(u1 << 16)
               + __uint_as_float(u2 << 16);
            ay = __uint_as_float(u0 & 0xFFFF0000u) + __uint_as_float(u1 & 0xFFFF0000u)
               + __uint_as_float(u2 & 0xFFFF0000u);
        } else {
            int lo = (bin == 0) ? 0 : offsets[bin-1];
            int hi = offsets[bin];
            ax = 0.f; ay = 0.f;
            for (int e = lo; e < hi; e += 4) {
                int s0 = slot_off[e];
                int s1 = slot_off[e+1];
                int s2 = slot_off[e+2];
                int s3 = slot_off[e+3];
                unsigned int u0 = Xb2[(unsigned)(s0 + l)];
                unsigned int u1 = Xb2[(unsigned)(s1 + l)];
                unsigned int u2 = Xb2[(unsigned)(s2 + l)];
                unsigned int u3 = Xb2[(unsigned)(s3 + l)];
                if (e+1 >= hi) u1 = 0u;
                if (e+2 >= hi) u2 = 0u;
                if (e+3 >= hi) u3 = 0u;
                ax += __uint_as_float(u0 << 16) + __uint_as_float(u1 << 16)
                    + __uint_as_float(u2 << 16) + __uint_as_float(u3 << 16);
                ay += __uint_as_float(u0 & 0xFFFF0000u) + __uint_as_float(u1 & 0xFFFF0000u)
                    + __uint_as_float(u2 & 0xFFFF0000u) + __uint_as_float(u3 & 0xFFFF0000u);
            }
        }
        float inv = 1.f / fmaxf((float)cnt, 1.f);
        res[bb] = packbf(ax*inv, ay*inv);
    }

    unsigned int* Mrow = Mc2 + (size_t)node*512;
    __builtin_nontemporal_store(res[0], &Mrow[(2*part+0)*64 + l]);
    __builtin_nontemporal_store(res[1], &Mrow[(2*part+1)*64 + l]);
}

// h(bf16)[Mpad][128] = relu( [Mc | Xb] @ Bt^T + bias )
// Col-split with XCD-pairing (R11-proven). Block = 64x64, BK=64, 16 KB LDS,
// gload_lds(16B), XOR swizzle (T21).
__global__ __launch_bounds__(256)
void mfma_gemm_kernel(const unsigned short* __restrict__ Mc,
                      const unsigned short* __restrict__ Xb,
                      const unsigned short* __restrict__ Btc,
                      const float* __restrict__ bias,
                      unsigned short* __restrict__ h, int MBrows) {
    __shared__ char ldsA[64*128];    // 8 KB
    __shared__ char ldsB[64*128];    // 8 KB

    int tid  = threadIdx.x;
    int lane = tid & 63;
    int wid  = tid >> 6;
    int rg = wid & 1, cg = wid >> 1;
    int fr = lane & 15, kb = lane >> 4;

    int blk = blockIdx.x;
    int q = blk >> 4, rem = blk & 15, c = rem >> 3, m = rem & 7;
    int rb = q*8 + m;
    if (rb >= MBrows) return;
    long m0 = (long)rb * 64;
    int colbase = c * 64;

    int lrow8 = lane >> 3;
    int lcb   = (lane & 7) * 16;

    f32x4 acc[2][2];
    #pragma unroll
    for (int mf = 0; mf < 2; ++mf)
        #pragma unroll
        for (int nf = 0; nf < 2; ++nf) acc[mf][nf] = f32x4{0.f,0.f,0.f,0.f};

    const char* McB = (const char*)Mc;
    const char* XbB = (const char*)Xb;
    const char* BtB = (const char*)Btc;

    for (int t = 0; t < 18; ++t) {
        #pragma unroll
        for (int i = 0; i < 2; ++i) {
            int row = wid*16 + i*8 + lrow8;
            int sw  = lcb ^ ((row & 7) << 4);
            const char* g = (t < 16)
                ? McB + (size_t)(m0 + row)*2048 + t*128 + sw
                : XbB + (size_t)(m0 + row)*256 + (t-16)*128 + sw;
            gload_lds16(g, &ldsA[wid*2048 + i*1024 + lane*16]);
        }
        #pragma unroll
        for (int i = 0; i < 2; ++i) {
            int col = wid*16 + i*8 + lrow8;
            int sw  = lcb ^ ((col & 7) << 4);
            const char* g = BtB + (size_t)(colbase + col)*2304 + t*128 + sw;
            gload_lds16(g, &ldsB[wid*2048 + i*1024 + lane*16]);
        }
        __syncthreads();

        bf16x8 af[2][2], bfr[2][2];
        #pragma unroll
        for (int mf = 0; mf < 2; ++mf) {
            int row = rg*32 + mf*16 + fr;
            #pragma unroll
            for (int kk = 0; kk < 2; ++kk) {
                int byte = row*128 + ((kk*64 + kb*16) ^ ((row & 7) << 4));
                af[mf][kk] = *reinterpret_cast<const bf16x8*>(&ldsA[byte]);
            }
        }
        #pragma unroll
        for (int nf = 0; nf < 2; ++nf) {
            int col = cg*32 + nf*16 + fr;
            #pragma unroll
            for (int kk = 0; kk < 2; ++kk) {
                int byte = col*128 + ((kk*64 + kb*16) ^ ((col & 7) << 4));
                bfr[nf][kk] = *reinterpret_cast<const bf16x8*>(&ldsB[byte]);
            }
        }
        #pragma unroll
        for (int kk = 0; kk < 2; ++kk)
            #pragma unroll
            for (int mf = 0; mf < 2; ++mf)
                #pragma unroll
                for (int nf = 0; nf < 2; ++nf)
                    acc[mf][nf] = __builtin_amdgcn_mfma_f32_16x16x32_bf16(
                        af[mf][kk], bfr[nf][kk], acc[mf][nf], 0, 0, 0);
        __syncthreads();
    }

    float bb[2];
    #pragma unroll
    for (int nf = 0; nf < 2; ++nf) bb[nf] = bias[colbase + cg*32 + nf*16 + fr];

    #pragma unroll
    for (int mf = 0; mf < 2; ++mf)
        #pragma unroll
        for (int q2 = 0; q2 < 4; ++q2) {
            long r = m0 + rg*32 + mf*16 + kb*4 + q2;
            unsigned short* hr = h + (size_t)r*128 + colbase + cg*32;
            #pragma unroll
            for (int nf = 0; nf < 2; ++nf)
                hr[nf*16 + fr] = f2bf(fmaxf(acc[mf][nf][q2] + bb[nf], 0.f));
        }
}

// Fused per-graph mean pool -> FC.
__global__ __launch_bounds__(512)
void pool_fc_kernel(const unsigned int* __restrict__ h2, const int* __restrict__ batch,
                    const float* __restrict__ fw, const float* __restrict__ fb,
                    float* __restrict__ out, int N, int C) {
    int g = blockIdx.x;
    int t = threadIdx.x;
    int lo = 0, hi = N;
    while (lo < hi) { int mid = (lo+hi) >> 1; if (batch[mid] < g) lo = mid+1; else hi = mid; }
    int s0 = lo;
    hi = N;
    while (lo < hi) { int mid = (lo+hi) >> 1; if (batch[mid] < g+1) lo = mid+1; else hi = mid; }
    int s1 = lo;

    int d2 = t & 63;
    float ax = 0.f, ay = 0.f;
    for (int row = s0 + (t >> 6); row < s1; row += 8) {
        unsigned int u = h2[(size_t)row*64 + d2];
        ax += bf2f((unsigned short)(u & 0xFFFFu));
        ay += bf2f((unsigned short)(u >> 16));
    }
    __shared__ float ps[128];
    if (t < 128) ps[t] = 0.f;
    __syncthreads();
    atomicAdd(&ps[2*d2],   ax);
    atomicAdd(&ps[2*d2+1], ay);
    __syncthreads();
    if (t < C) {
        float inv = 1.f / fmaxf((float)(s1 - s0), 1.f);
        float s = 0.f;
        #pragma unroll 4
        for (int k = 0; k < 128; ++k) s += ps[k] * fw[(size_t)k*C + t];
        out[(size_t)g*C + t] = s * inv + fb[t];
    }
}

extern "C" void kernel_launch(void* const* d_in, const int* in_sizes, int n_in,
                              void* d_out, int out_size, void* d_ws, size_t ws_size,
                              hipStream_t stream) {
    const float* x       = (const float*)d_in[0];
    const int*   eindex  = (const int*)  d_in[1];
    const int*   etype   = (const int*)  d_in[2];
    const int*   batch   = (const int*)  d_in[4];
    const float* basis   = (const float*)d_in[6];
    const float* comp    = (const float*)d_in[7];
    const float* root    = (const float*)d_in[8];
    const float* bias    = (const float*)d_in[9];
    const float* fc_w    = (const float*)d_in[10];
    const float* fc_b    = (const float*)d_in[11];

    int N  = in_sizes[4];          // 50000
    int E  = in_sizes[2];          // 600000
    int C  = in_sizes[11];         // 16
    int G  = out_size / C;         // 64
    int IO = in_sizes[8];          // 16384
    int B  = in_sizes[6] / IO;     // 4
    int R  = in_sizes[7] / B;      // 8
    int NR = N * R;
    int MB = ceil_div(N, 64);      // 64-row GEMM row-blocks (782)
    int Mpad = MB * 64;
    int grid_gemm = ceil_div(MB, 8) * 16;   // XCD-paired col-split grid (1568)

    const int* src = eindex;
    const int* dst = eindex + E;

    // ---- workspace layout (~140 MB) ----
    char* base = (char*)d_ws;
    size_t off = 0;
    auto alloc = [&](size_t bytes) -> char* {
        char* p = base + off;
        off = align_up(off + bytes, 256);
        return p;
    };
    unsigned short* Bt  = (unsigned short*)alloc(sizeof(unsigned short)*128*1152);
    int*   cnt      = (int*)  alloc(sizeof(int)*(size_t)NR);
    int*   offsets  = (int*)  alloc(sizeof(int)*((size_t)NR+1));
    int*   bsums    = (int*)  alloc(sizeof(int)*1024);
    int4*  binfo    = (int4*) alloc(sizeof(int4)*(size_t)NR);
    int*   slot_off = (int*)  alloc(sizeof(int)*((size_t)E+4));
    unsigned short* h  = (unsigned short*)alloc(sizeof(unsigned short)*(size_t)Mpad*128);
    unsigned short* Xb = (unsigned short*)alloc(sizeof(unsigned short)*(size_t)Mpad*128);
    unsigned short* Mc = (unsigned short*)alloc(sizeof(unsigned short)*(size_t)Mpad*1024);

    // ---- pipeline (9 launches) ----
    pre_kernel<<<1024,256,0,stream>>>(comp, basis, root, Bt, B,
                                      x, (unsigned int*)Xb, N, cnt, NR);
    count_kernel<<<ceil_div(E,256),256,0,stream>>>(dst, etype, cnt, E, R);

    int nb = ceil_div(NR, 1024);
    scan_block_kernel<<<nb,256,0,stream>>>(cnt, offsets, bsums, binfo, NR);
    scan_block_kernel<<<1,256,0,stream>>>(bsums, bsums, nullptr, nullptr, nb);
    scan_add_kernel<<<ceil_div(NR,256),256,0,stream>>>(offsets, bsums, NR, E);

    fill_kernel<<<ceil_div(E,256),256,0,stream>>>(src, dst, etype, offsets, cnt, binfo,
                                                  slot_off, E, R);

    aggregate_kernel<<<ceil_div(N*4*64,256),256,0,stream>>>(offsets, slot_off, binfo,
                                                            (const unsigned int*)Xb,
                                                            (unsigned int*)Mc, N);

    mfma_gemm_kernel<<<grid_gemm,256,0,stream>>>(Mc, Xb, Bt, bias, h, MB);

    pool_fc_kernel<<<G,512,0,stream>>>((const unsigned int*)h, batch, fc_w, fc_b,
                                       (float*)d_out, N, C);
}

// Round 16
// 213.577 us; speedup vs baseline: 1.2242x; 1.2242x over previous
//
#include <hip/hip_runtime.h>

static inline int ceil_div(int a, int b){ return (a+b-1)/b; }
static inline size_t align_up(size_t x, size_t a){ return (x + a - 1) / a * a; }

typedef __bf16 bf16x8 __attribute__((ext_vector_type(8)));
typedef float  f32x4  __attribute__((ext_vector_type(4)));

static __device__ inline unsigned short f2bf(float f){
    unsigned int u = __float_as_uint(f);
    unsigned int lsb = (u >> 16) & 1u;
    u += 0x7FFFu + lsb;
    return (unsigned short)(u >> 16);
}
static __device__ inline float bf2f(unsigned short b){
    return __uint_as_float(((unsigned int)b) << 16);
}
static __device__ inline unsigned int packbf(float a, float b){
    return (unsigned int)f2bf(a) | ((unsigned int)f2bf(b) << 16);
}

// async 16B global->LDS (wave-uniform LDS base + lane*16 layout)
static __device__ inline void gload_lds16(const void* g, void* l) {
    __builtin_amdgcn_global_load_lds(
        (const __attribute__((address_space(1))) unsigned int*)g,
        (__attribute__((address_space(3))) unsigned int*)l, 16, 0, 0);
}

// Merged prologue: zero cnt | build Bt | convert x -> Xb bf16. All independent.
__global__ __launch_bounds__(256)
void pre_kernel(const float* __restrict__ comp, const float* __restrict__ basis,
                const float* __restrict__ root, unsigned short* __restrict__ Bt, int B,
                const float* __restrict__ x, unsigned int* __restrict__ Xb2, int N,
                int* __restrict__ cnt, int NR) {
    int gtid = blockIdx.x*blockDim.x + threadIdx.x;
    int gsz  = gridDim.x*blockDim.x;
    for (int i = gtid; i < NR; i += gsz) cnt[i] = 0;
    for (int idx = gtid; idx < 128*1152; idx += gsz) {
        int o = idx / 1152, kk = idx - o*1152;
        float val;
        if (kk < 1024) {
            int r = kk >> 7, i = kk & 127;
            val = 0.f;
            for (int b = 0; b < B; ++b)
                val += comp[r*B+b] * basis[((size_t)b*128 + i)*128 + o];
        } else {
            val = root[(size_t)(kk-1024)*128 + o];
        }
        Bt[idx] = f2bf(val);
    }
    for (int tt = gtid; tt < N*64; tt += gsz) {
        int n = tt >> 6, l = tt & 63;
        float2 v = reinterpret_cast<const float2*>(x + (size_t)n*128)[l];
        Xb2[(size_t)n*64 + l] = packbf(v.x, v.y);
    }
}

__global__ void count_kernel(const int* __restrict__ dst, const int* __restrict__ et,
                             int* __restrict__ cnt, int E, int R) {
    int e = blockIdx.x*blockDim.x + threadIdx.x;
    if (e >= E) return;
    atomicAdd(&cnt[(size_t)dst[e]*R + et[e]], 1);
}

__global__ __launch_bounds__(256)
void scan_block_kernel(const int* __restrict__ in, int* __restrict__ out,
                       int* __restrict__ bsums, int n) {
    __shared__ int tsum[256];
    int t = threadIdx.x;
    int idx0 = blockIdx.x*1024 + t*4;
    int v0 = (idx0+0 < n) ? in[idx0+0] : 0;
    int v1 = (idx0+1 < n) ? in[idx0+1] : 0;
    int v2 = (idx0+2 < n) ? in[idx0+2] : 0;
    int v3 = (idx0+3 < n) ? in[idx0+3] : 0;
    int s = v0+v1+v2+v3;
    tsum[t] = s; __syncthreads();
    for (int off = 1; off < 256; off <<= 1) {
        int x = (t >= off) ? tsum[t-off] : 0;
        __syncthreads();
        tsum[t] += x;
        __syncthreads();
    }
    int run = tsum[t] - s;
    if (idx0+0 < n) out[idx0+0] = run; run += v0;
    if (idx0+1 < n) out[idx0+1] = run; run += v1;
    if (idx0+2 < n) out[idx0+2] = run; run += v2;
    if (idx0+3 < n) out[idx0+3] = run;
    if (bsums && t == 255) bsums[blockIdx.x] = tsum[255];
}

__global__ void scan_add_kernel(int* __restrict__ out, const int* __restrict__ bs,
                                int n, int total) {
    int i = blockIdx.x*blockDim.x + threadIdx.x;
    if (i < n) out[i] += bs[i >> 10];
    if (i == 0) out[n] = total;
}

// slot = atomicAdd(&offsets[bin],1): offsets mutates into shifted-by-one bounds.
// slot_off stores PRE-SHIFTED u32 index (src<<6). Pad of 4 zeros after E.
__global__ void fill_kernel(const int* __restrict__ src, const int* __restrict__ dst,
                            const int* __restrict__ et, int* __restrict__ offsets,
                            int* __restrict__ slot_off, int E, int R) {
    int e = blockIdx.x*blockDim.x + threadIdx.x;
    if (e >= E) return;
    if (e < 4) slot_off[E + e] = 0;
    int bin = dst[e]*R + et[e];
    int slot = atomicAdd(&offsets[bin], 1);
    slot_off[slot] = src[e] << 6;
}

// 4 waves per node, 2 bins per wave. Bounds shifted-by-one: bin b = [off[b-1], off[b]).
// Masked always-4-wide gather, unclamped (slot_off padded). R12/R14-proven form.
__global__ __launch_bounds__(256)
void aggregate_kernel(const int* __restrict__ offsets, const int* __restrict__ slot_off,
                      const unsigned int* __restrict__ Xb2, unsigned int* __restrict__ Mc2,
                      int N) {
    int gw = (int)((blockIdx.x*blockDim.x + threadIdx.x) >> 6);
    int node = gw >> 2, part = gw & 3;
    if (node >= N) return;
    int l = threadIdx.x & 63;
    int base = node*8 + part*2;
    int lo   = (base == 0) ? 0 : offsets[base-1];
    int bmid = offsets[base];
    int hi   = offsets[base+1];

    float ax0=0.f, ay0=0.f, ax1=0.f, ay1=0.f;

#define ACC2(E_, U_) { \
    float vx_ = bf2f((unsigned short)((U_) & 0xFFFFu)); \
    float vy_ = bf2f((unsigned short)((U_) >> 16)); \
    if ((E_) < bmid) { ax0 += vx_; ay0 += vy_; } \
    else             { ax1 += vx_; ay1 += vy_; } }

    for (int e = lo; e < hi; e += 4) {
        int s0 = slot_off[e];
        int s1 = slot_off[e+1];
        int s2 = slot_off[e+2];
        int s3 = slot_off[e+3];
        unsigned int u0 = Xb2[(unsigned)(s0 + l)];
        unsigned int u1 = Xb2[(unsigned)(s1 + l)];
        unsigned int u2 = Xb2[(unsigned)(s2 + l)];
        unsigned int u3 = Xb2[(unsigned)(s3 + l)];
        if (e+1 >= hi) u1 = 0u;        // wave-uniform masks
        if (e+2 >= hi) u2 = 0u;
        if (e+3 >= hi) u3 = 0u;
        ACC2(e+0, u0) ACC2(e+1, u1) ACC2(e+2, u2) ACC2(e+3, u3)
    }
#undef ACC2

    unsigned int* Mrow = Mc2 + (size_t)node*512;
    float i0 = 1.f/fmaxf((float)(bmid-lo), 1.f);
    float i1 = 1.f/fmaxf((float)(hi-bmid), 1.f);
    __builtin_nontemporal_store(packbf(ax0*i0, ay0*i0), &Mrow[(2*part+0)*64 + l]);
    __builtin_nontemporal_store(packbf(ax1*i1, ay1*i1), &Mrow[(2*part+1)*64 + l]);
}

// h(bf16)[Mpad][128] = relu( [Mc | Xb] @ Bt^T + bias )
// Col-split with XCD-pairing (R11-proven geometry) + COUNTED-VMCNT DOUBLE BUFFER:
// stage(t+1) issued async; raw s_barrier + inline-asm s_waitcnt vmcnt(4) -- next-tile
// loads stay in flight across both barriers (no vmcnt(0) drain; fixes R12's bug).
// Race audit: buf read in iter t-1 is sealed by the end-of-compute barrier before
// iter t's stage-issue; each wave's own buf-writes proven done by its vmcnt(4) before
// the pre-compute barrier; no ds_writes exist so raw barriers suffice.
__global__ __launch_bounds__(256)
void mfma_gemm_kernel(const unsigned short* __restrict__ Mc,
                      const unsigned short* __restrict__ Xb,
                      const unsigned short* __restrict__ Btc,
                      const float* __restrict__ bias,
                      unsigned short* __restrict__ h, int MBrows) {
    __shared__ char ldsA[2][64*128];    // 2 x 8 KB
    __shared__ char ldsB[2][64*128];    // 2 x 8 KB

    int tid  = threadIdx.x;
    int lane = tid & 63;
    int wid  = tid >> 6;
    int rg = wid & 1, cg = wid >> 1;
    int fr = lane & 15, kb = lane >> 4;

    int blk = blockIdx.x;
    int q = blk >> 4, rem = blk & 15, c = rem >> 3, m = rem & 7;
    int rb = q*8 + m;
    if (rb >= MBrows) return;
    long m0 = (long)rb * 64;
    int colbase = c * 64;

    int lrow8 = lane >> 3;            // 0..7 row within a gload issue
    int lcb   = (lane & 7) * 16;      // 16B slot within 128B row

    f32x4 acc[2][2];
    #pragma unroll
    for (int mf = 0; mf < 2; ++mf)
        #pragma unroll
        for (int nf = 0; nf < 2; ++nf) acc[mf][nf] = f32x4{0.f,0.f,0.f,0.f};

    const char* McB = (const char*)Mc;
    const char* XbB = (const char*)Xb;
    const char* BtB = (const char*)Btc;

    auto stage = [&](int t, int buf) {
        #pragma unroll
        for (int i = 0; i < 2; ++i) {
            int row = wid*16 + i*8 + lrow8;
            int sw  = lcb ^ ((row & 7) << 4);
            const char* g = (t < 16)
                ? McB + (size_t)(m0 + row)*2048 + t*128 + sw
                : XbB + (size_t)(m0 + row)*256 + (t-16)*128 + sw;
            gload_lds16(g, &ldsA[buf][wid*2048 + i*1024 + lane*16]);
        }
        #pragma unroll
        for (int i = 0; i < 2; ++i) {
            int col = wid*16 + i*8 + lrow8;       // local col 0..63
            int sw  = lcb ^ ((col & 7) << 4);
            const char* g = BtB + (size_t)(colbase + col)*2304 + t*128 + sw;
            gload_lds16(g, &ldsB[buf][wid*2048 + i*1024 + lane*16]);
        }
    };

    stage(0, 0);
    asm volatile("s_waitcnt vmcnt(0)" ::: "memory");
    __builtin_amdgcn_s_barrier();

    for (int t = 0; t < 18; ++t) {
        int cur = t & 1;
        if (t + 1 < 18) {
            stage(t + 1, cur ^ 1);                       // async: 4 loads/thread
            asm volatile("s_waitcnt vmcnt(4)" ::: "memory");  // tile-t writes done
        } else {
            asm volatile("s_waitcnt vmcnt(0)" ::: "memory");
        }
        __builtin_amdgcn_sched_barrier(0);
        __builtin_amdgcn_s_barrier();                    // everyone's tile-t complete
        __builtin_amdgcn_sched_barrier(0);

        bf16x8 af[2][2], bfr[2][2];
        #pragma unroll
        for (int mf = 0; mf < 2; ++mf) {
            int row = rg*32 + mf*16 + fr;
            #pragma unroll
            for (int kk = 0; kk < 2; ++kk) {
                int byte = row*128 + ((kk*64 + kb*16) ^ ((row & 7) << 4));
                af[mf][kk] = *reinterpret_cast<const bf16x8*>(&ldsA[cur][byte]);
            }
        }
        #pragma unroll
        for (int nf = 0; nf < 2; ++nf) {
            int col = cg*32 + nf*16 + fr;
            #pragma unroll
            for (int kk = 0; kk < 2; ++kk) {
                int byte = col*128 + ((kk*64 + kb*16) ^ ((col & 7) << 4));
                bfr[nf][kk] = *reinterpret_cast<const bf16x8*>(&ldsB[cur][byte]);
            }
        }
        #pragma unroll
        for (int kk = 0; kk < 2; ++kk)
            #pragma unroll
            for (int mf = 0; mf < 2; ++mf)
                #pragma unroll
                for (int nf = 0; nf < 2; ++nf)
                    acc[mf][nf] = __builtin_amdgcn_mfma_f32_16x16x32_bf16(
                        af[mf][kk], bfr[nf][kk], acc[mf][nf], 0, 0, 0);

        __builtin_amdgcn_sched_barrier(0);
        __builtin_amdgcn_s_barrier();                    // reads of buf[cur] sealed
    }

    float bb[2];
    #pragma unroll
    for (int nf = 0; nf < 2; ++nf) bb[nf] = bias[colbase + cg*32 + nf*16 + fr];

    #pragma unroll
    for (int mf = 0; mf < 2; ++mf)
        #pragma unroll
        for (int q2 = 0; q2 < 4; ++q2) {
            long r = m0 + rg*32 + mf*16 + kb*4 + q2;
            unsigned short* hr = h + (size_t)r*128 + colbase + cg*32;
            #pragma unroll
            for (int nf = 0; nf < 2; ++nf)
                hr[nf*16 + fr] = f2bf(fmaxf(acc[mf][nf][q2] + bb[nf], 0.f));
        }
}

// Fused per-graph mean pool -> FC.
__global__ __launch_bounds__(512)
void pool_fc_kernel(const unsigned int* __restrict__ h2, const int* __restrict__ batch,
                    const float* __restrict__ fw, const float* __restrict__ fb,
                    float* __restrict__ out, int N, int C) {
    int g = blockIdx.x;
    int t = threadIdx.x;
    int lo = 0, hi = N;
    while (lo < hi) { int mid = (lo+hi) >> 1; if (batch[mid] < g) lo = mid+1; else hi = mid; }
    int s0 = lo;
    hi = N;
    while (lo < hi) { int mid = (lo+hi) >> 1; if (batch[mid] < g+1) lo = mid+1; else hi = mid; }
    int s1 = lo;

    int d2 = t & 63;
    float ax = 0.f, ay = 0.f;
    for (int row = s0 + (t >> 6); row < s1; row += 8) {
        unsigned int u = h2[(size_t)row*64 + d2];
        ax += bf2f((unsigned short)(u & 0xFFFFu));
        ay += bf2f((unsigned short)(u >> 16));
    }
    __shared__ float ps[128];
    if (t < 128) ps[t] = 0.f;
    __syncthreads();
    atomicAdd(&ps[2*d2],   ax);
    atomicAdd(&ps[2*d2+1], ay);
    __syncthreads();
    if (t < C) {
        float inv = 1.f / fmaxf((float)(s1 - s0), 1.f);
        float s = 0.f;
        #pragma unroll 4
        for (int k = 0; k < 128; ++k) s += ps[k] * fw[(size_t)k*C + t];
        out[(size_t)g*C + t] = s * inv + fb[t];
    }
}

extern "C" void kernel_launch(void* const* d_in, const int* in_sizes, int n_in,
                              void* d_out, int out_size, void* d_ws, size_t ws_size,
                              hipStream_t stream) {
    const float* x       = (const float*)d_in[0];
    const int*   eindex  = (const int*)  d_in[1];
    const int*   etype   = (const int*)  d_in[2];
    const int*   batch   = (const int*)  d_in[4];
    const float* basis   = (const float*)d_in[6];
    const float* comp    = (const float*)d_in[7];
    const float* root    = (const float*)d_in[8];
    const float* bias    = (const float*)d_in[9];
    const float* fc_w    = (const float*)d_in[10];
    const float* fc_b    = (const float*)d_in[11];

    int N  = in_sizes[4];          // 50000
    int E  = in_sizes[2];          // 600000
    int C  = in_sizes[11];         // 16
    int G  = out_size / C;         // 64
    int IO = in_sizes[8];          // 16384
    int B  = in_sizes[6] / IO;     // 4
    int R  = in_sizes[7] / B;      // 8
    int NR = N * R;
    int MB = ceil_div(N, 64);      // 64-row GEMM row-blocks (782)
    int Mpad = MB * 64;
    int grid_gemm = ceil_div(MB, 8) * 16;   // XCD-paired col-split grid (1568)

    const int* src = eindex;
    const int* dst = eindex + E;

    // ---- workspace layout (~134 MB) ----
    char* base = (char*)d_ws;
    size_t off = 0;
    auto alloc = [&](size_t bytes) -> char* {
        char* p = base + off;
        off = align_up(off + bytes, 256);
        return p;
    };
    unsigned short* Bt  = (unsigned short*)alloc(sizeof(unsigned short)*128*1152);
    int*   cnt      = (int*)  alloc(sizeof(int)*(size_t)NR);
    int*   offsets  = (int*)  alloc(sizeof(int)*((size_t)NR+1));
    int*   bsums    = (int*)  alloc(sizeof(int)*1024);
    int*   slot_off = (int*)  alloc(sizeof(int)*((size_t)E+4));
    unsigned short* h  = (unsigned short*)alloc(sizeof(unsigned short)*(size_t)Mpad*128);
    unsigned short* Xb = (unsigned short*)alloc(sizeof(unsigned short)*(size_t)Mpad*128);
    unsigned short* Mc = (unsigned short*)alloc(sizeof(unsigned short)*(size_t)Mpad*1024);

    // ---- pipeline (9 launches) ----
    pre_kernel<<<1024,256,0,stream>>>(comp, basis, root, Bt, B,
                                      x, (unsigned int*)Xb, N, cnt, NR);
    count_kernel<<<ceil_div(E,256),256,0,stream>>>(dst, etype, cnt, E, R);

    int nb = ceil_div(NR, 1024);
    scan_block_kernel<<<nb,256,0,stream>>>(cnt, offsets, bsums, NR);
    scan_block_kernel<<<1,256,0,stream>>>(bsums, bsums, nullptr, nb);
    scan_add_kernel<<<ceil_div(NR,256),256,0,stream>>>(offsets, bsums, NR, E);

    fill_kernel<<<ceil_div(E,256),256,0,stream>>>(src, dst, etype, offsets, slot_off, E, R);

    aggregate_kernel<<<ceil_div(N*4*64,256),256,0,stream>>>(offsets, slot_off,
                                                            (const unsigned int*)Xb,
                                                            (unsigned int*)Mc, N);

    mfma_gemm_kernel<<<grid_gemm,256,0,stream>>>(Mc, Xb, Bt, bias, h, MB);

    pool_fc_kernel<<<G,512,0,stream>>>((const unsigned int*)h, batch, fc_w, fc_b,
                                       (float*)d_out, N, C);
}

// Round 17
// 193.372 us; speedup vs baseline: 1.3521x; 1.1045x over previous
//
#include <hip/hip_runtime.h>

static inline int ceil_div(int a, int b){ return (a+b-1)/b; }
static inline size_t align_up(size_t x, size_t a){ return (x + a - 1) / a * a; }

typedef __bf16 bf16x8 __attribute__((ext_vector_type(8)));
typedef float  f32x4  __attribute__((ext_vector_type(4)));

static __device__ inline unsigned short f2bf(float f){
    unsigned int u = __float_as_uint(f);
    unsigned int lsb = (u >> 16) & 1u;
    u += 0x7FFFu + lsb;
    return (unsigned short)(u >> 16);
}
static __device__ inline float bf2f(unsigned short b){
    return __uint_as_float(((unsigned int)b) << 16);
}
static __device__ inline unsigned int packbf(float a, float b){
    return (unsigned int)f2bf(a) | ((unsigned int)f2bf(b) << 16);
}

// async 16B global->LDS (wave-uniform LDS base + lane*16 layout)
static __device__ inline void gload_lds16(const void* g, void* l) {
    __builtin_amdgcn_global_load_lds(
        (const __attribute__((address_space(1))) unsigned int*)g,
        (__attribute__((address_space(3))) unsigned int*)l, 16, 0, 0);
}

// Merged prologue: zero cnt+psum | build Bt | convert x -> Xb bf16. All independent.
__global__ __launch_bounds__(256)
void pre_kernel(const float* __restrict__ comp, const float* __restrict__ basis,
                const float* __restrict__ root, unsigned short* __restrict__ Bt, int B,
                const float* __restrict__ x, unsigned int* __restrict__ Xb2, int N,
                int* __restrict__ cnt, int NR, float* __restrict__ psum, int G) {
    int gtid = blockIdx.x*blockDim.x + threadIdx.x;
    int gsz  = gridDim.x*blockDim.x;
    for (int i = gtid; i < NR; i += gsz) cnt[i] = 0;
    for (int i = gtid; i < G*128; i += gsz) psum[i] = 0.f;
    for (int idx = gtid; idx < 128*1152; idx += gsz) {
        int o = idx / 1152, kk = idx - o*1152;
        float val;
        if (kk < 1024) {
            int r = kk >> 7, i = kk & 127;
            val = 0.f;
            for (int b = 0; b < B; ++b)
                val += comp[r*B+b] * basis[((size_t)b*128 + i)*128 + o];
        } else {
            val = root[(size_t)(kk-1024)*128 + o];
        }
        Bt[idx] = f2bf(val);
    }
    for (int tt = gtid; tt < N*64; tt += gsz) {
        int n = tt >> 6, l = tt & 63;
        float2 v = reinterpret_cast<const float2*>(x + (size_t)n*128)[l];
        Xb2[(size_t)n*64 + l] = packbf(v.x, v.y);
    }
}

__global__ void count_kernel(const int* __restrict__ dst, const int* __restrict__ et,
                             int* __restrict__ cnt, int E, int R) {
    int e = blockIdx.x*blockDim.x + threadIdx.x;
    if (e >= E) return;
    atomicAdd(&cnt[(size_t)dst[e]*R + et[e]], 1);
}

__global__ __launch_bounds__(256)
void scan_block_kernel(const int* __restrict__ in, int* __restrict__ out,
                       int* __restrict__ bsums, int n) {
    __shared__ int tsum[256];
    int t = threadIdx.x;
    int idx0 = blockIdx.x*1024 + t*4;
    int v0 = (idx0+0 < n) ? in[idx0+0] : 0;
    int v1 = (idx0+1 < n) ? in[idx0+1] : 0;
    int v2 = (idx0+2 < n) ? in[idx0+2] : 0;
    int v3 = (idx0+3 < n) ? in[idx0+3] : 0;
    int s = v0+v1+v2+v3;
    tsum[t] = s; __syncthreads();
    for (int off = 1; off < 256; off <<= 1) {
        int x = (t >= off) ? tsum[t-off] : 0;
        __syncthreads();
        tsum[t] += x;
        __syncthreads();
    }
    int run = tsum[t] - s;
    if (idx0+0 < n) out[idx0+0] = run; run += v0;
    if (idx0+1 < n) out[idx0+1] = run; run += v1;
    if (idx0+2 < n) out[idx0+2] = run; run += v2;
    if (idx0+3 < n) out[idx0+3] = run;
    if (bsums && t == 255) bsums[blockIdx.x] = tsum[255];
}

__global__ void scan_add_kernel(int* __restrict__ out, const int* __restrict__ bs,
                                int n, int total) {
    int i = blockIdx.x*blockDim.x + threadIdx.x;
    if (i < n) out[i] += bs[i >> 10];
    if (i == 0) out[n] = total;
}

// slot = atomicAdd(&offsets[bin],1): offsets mutates into shifted-by-one bounds.
// slot_off stores PRE-SHIFTED u32 index (src<<6). Pad of 4 zeros after E.
__global__ void fill_kernel(const int* __restrict__ src, const int* __restrict__ dst,
                            const int* __restrict__ et, int* __restrict__ offsets,
                            int* __restrict__ slot_off, int E, int R) {
    int e = blockIdx.x*blockDim.x + threadIdx.x;
    if (e >= E) return;
    if (e < 4) slot_off[E + e] = 0;
    int bin = dst[e]*R + et[e];
    int slot = atomicAdd(&offsets[bin], 1);
    slot_off[slot] = src[e] << 6;
}

// 4 waves per node, 2 bins per wave. Bounds shifted-by-one: bin b = [off[b-1], off[b]).
// Masked always-4-wide gather, unclamped (slot_off padded). R12/R14-proven form.
__global__ __launch_bounds__(256)
void aggregate_kernel(const int* __restrict__ offsets, const int* __restrict__ slot_off,
                      const unsigned int* __restrict__ Xb2, unsigned int* __restrict__ Mc2,
                      int N) {
    int gw = (int)((blockIdx.x*blockDim.x + threadIdx.x) >> 6);
    int node = gw >> 2, part = gw & 3;
    if (node >= N) return;
    int l = threadIdx.x & 63;
    int base = node*8 + part*2;
    int lo   = (base == 0) ? 0 : offsets[base-1];
    int bmid = offsets[base];
    int hi   = offsets[base+1];

    float ax0=0.f, ay0=0.f, ax1=0.f, ay1=0.f;

#define ACC2(E_, U_) { \
    float vx_ = bf2f((unsigned short)((U_) & 0xFFFFu)); \
    float vy_ = bf2f((unsigned short)((U_) >> 16)); \
    if ((E_) < bmid) { ax0 += vx_; ay0 += vy_; } \
    else             { ax1 += vx_; ay1 += vy_; } }

    for (int e = lo; e < hi; e += 4) {
        int s0 = slot_off[e];
        int s1 = slot_off[e+1];
        int s2 = slot_off[e+2];
        int s3 = slot_off[e+3];
        unsigned int u0 = Xb2[(unsigned)(s0 + l)];
        unsigned int u1 = Xb2[(unsigned)(s1 + l)];
        unsigned int u2 = Xb2[(unsigned)(s2 + l)];
        unsigned int u3 = Xb2[(unsigned)(s3 + l)];
        if (e+1 >= hi) u1 = 0u;        // wave-uniform masks
        if (e+2 >= hi) u2 = 0u;
        if (e+3 >= hi) u3 = 0u;
        ACC2(e+0, u0) ACC2(e+1, u1) ACC2(e+2, u2) ACC2(e+3, u3)
    }
#undef ACC2

    unsigned int* Mrow = Mc2 + (size_t)node*512;
    float i0 = 1.f/fmaxf((float)(bmid-lo), 1.f);
    float i1 = 1.f/fmaxf((float)(hi-bmid), 1.f);
    __builtin_nontemporal_store(packbf(ax0*i0, ay0*i0), &Mrow[(2*part+0)*64 + l]);
    __builtin_nontemporal_store(packbf(ax1*i1, ay1*i1), &Mrow[(2*part+1)*64 + l]);
}

// GEMM + fused pooling epilogue. NO h buffer:
// psum[g][col] += sum over rows of graph g of relu([Mc|Xb] @ Bt^T + bias).
// Col-split with XCD-pairing (R11-proven geometry), R14-proven 2-barrier loop.
// Epilogue: relu tile -> LDS f32 [64][66] (reuses staging LDS after final barrier),
// 4 threads/col sweep 16 rows each segmented by sorted batch[], atomicAdd per
// (graph,col) partial (~256 atomics/block over a 32 KB psum -> no contention).
__global__ __launch_bounds__(256)
void mfma_gemm_kernel(const unsigned short* __restrict__ Mc,
                      const unsigned short* __restrict__ Xb,
                      const unsigned short* __restrict__ Btc,
                      const float* __restrict__ bias,
                      const int* __restrict__ batch,
                      float* __restrict__ psum, int Nrows, int MBrows) {
    __shared__ char ldsRaw[32768];   // [0,16K): A bufs 0/1; [16K,32K): B bufs 0/1
    auto ldsA = [&](int buf) -> char* { return ldsRaw + buf*8192; };
    auto ldsB = [&](int buf) -> char* { return ldsRaw + 16384 + buf*8192; };

    int tid  = threadIdx.x;
    int lane = tid & 63;
    int wid  = tid >> 6;
    int rg = wid & 1, cg = wid >> 1;
    int fr = lane & 15, kb = lane >> 4;

    int blk = blockIdx.x;
    int q = blk >> 4, rem = blk & 15, c = rem >> 3, m = rem & 7;
    int rb = q*8 + m;
    if (rb >= MBrows) return;
    long m0 = (long)rb * 64;
    int colbase = c * 64;

    int lrow8 = lane >> 3;            // 0..7 row within a gload issue
    int lcb   = (lane & 7) * 16;      // 16B slot within 128B row

    f32x4 acc[2][2];
    #pragma unroll
    for (int mf = 0; mf < 2; ++mf)
        #pragma unroll
        for (int nf = 0; nf < 2; ++nf) acc[mf][nf] = f32x4{0.f,0.f,0.f,0.f};

    const char* McB = (const char*)Mc;
    const char* XbB = (const char*)Xb;
    const char* BtB = (const char*)Btc;

    for (int t = 0; t < 18; ++t) {
        int cur = t & 1;
        #pragma unroll
        for (int i = 0; i < 2; ++i) {
            int row = wid*16 + i*8 + lrow8;
            int sw  = lcb ^ ((row & 7) << 4);
            const char* g = (t < 16)
                ? McB + (size_t)(m0 + row)*2048 + t*128 + sw
                : XbB + (size_t)(m0 + row)*256 + (t-16)*128 + sw;
            gload_lds16(g, ldsA(cur) + wid*2048 + i*1024 + lane*16);
        }
        #pragma unroll
        for (int i = 0; i < 2; ++i) {
            int col = wid*16 + i*8 + lrow8;       // local col 0..63
            int sw  = lcb ^ ((col & 7) << 4);
            const char* g = BtB + (size_t)(colbase + col)*2304 + t*128 + sw;
            gload_lds16(g, ldsB(cur) + wid*2048 + i*1024 + lane*16);
        }
        __syncthreads();

        bf16x8 af[2][2], bfr[2][2];
        #pragma unroll
        for (int mf = 0; mf < 2; ++mf) {
            int row = rg*32 + mf*16 + fr;
            #pragma unroll
            for (int kk = 0; kk < 2; ++kk) {
                int byte = row*128 + ((kk*64 + kb*16) ^ ((row & 7) << 4));
                af[mf][kk] = *reinterpret_cast<const bf16x8*>(ldsA(cur) + byte);
            }
        }
        #pragma unroll
        for (int nf = 0; nf < 2; ++nf) {
            int col = cg*32 + nf*16 + fr;         // local col
            #pragma unroll
            for (int kk = 0; kk < 2; ++kk) {
                int byte = col*128 + ((kk*64 + kb*16) ^ ((col & 7) << 4));
                bfr[nf][kk] = *reinterpret_cast<const bf16x8*>(ldsB(cur) + byte);
            }
        }
        #pragma unroll
        for (int kk = 0; kk < 2; ++kk)
            #pragma unroll
            for (int mf = 0; mf < 2; ++mf)
                #pragma unroll
                for (int nf = 0; nf < 2; ++nf)
                    acc[mf][nf] = __builtin_amdgcn_mfma_f32_16x16x32_bf16(
                        af[mf][kk], bfr[nf][kk], acc[mf][nf], 0, 0, 0);
        __syncthreads();
    }

    // ---- fused pooling epilogue ----
    float bb[2];
    #pragma unroll
    for (int nf = 0; nf < 2; ++nf) bb[nf] = bias[colbase + cg*32 + nf*16 + fr];

    float* ldsF = (float*)ldsRaw;     // [64][66] f32 = 16896 B (staging LDS is dead)
    #pragma unroll
    for (int mf = 0; mf < 2; ++mf)
        #pragma unroll
        for (int q2 = 0; q2 < 4; ++q2) {
            int rl = rg*32 + mf*16 + kb*4 + q2;
            #pragma unroll
            for (int nf = 0; nf < 2; ++nf) {
                int cl = cg*32 + nf*16 + fr;
                ldsF[rl*66 + cl] = fmaxf(acc[mf][nf][q2] + bb[nf], 0.f);
            }
        }
    __syncthreads();

    int col = tid & 63, rq = tid >> 6;      // 4 threads per column, 16 rows each
    float partial = 0.f;
    int gcur = -1;
    for (int i = 0; i < 16; ++i) {
        long row = m0 + rq*16 + i;
        if (row >= Nrows) break;
        int g = batch[row];
        if (g != gcur) {
            if (gcur >= 0) atomicAdd(&psum[(size_t)gcur*128 + colbase + col], partial);
            gcur = g; partial = 0.f;
        }
        partial += ldsF[(rq*16 + i)*66 + col];
    }
    if (gcur >= 0) atomicAdd(&psum[(size_t)gcur*128 + colbase + col], partial);
}

// out[g][c] = (psum[g]/cnt_g) @ fc_w + fc_b   (G*C threads; cnt via binary search)
__global__ void fc_kernel(const float* __restrict__ psum, const int* __restrict__ batch,
                          const float* __restrict__ fw, const float* __restrict__ fb,
                          float* __restrict__ out, int N, int G, int C) {
    int idx = blockIdx.x*blockDim.x + threadIdx.x;
    if (idx >= G*C) return;
    int g = idx / C, cc = idx - g*C;
    int lo = 0, hi = N;
    while (lo < hi) { int mid = (lo+hi) >> 1; if (batch[mid] < g) lo = mid+1; else hi = mid; }
    int s0 = lo;
    hi = N;
    while (lo < hi) { int mid = (lo+hi) >> 1; if (batch[mid] < g+1) lo = mid+1; else hi = mid; }
    float inv = 1.f / fmaxf((float)(lo - s0), 1.f);
    float s = fb[cc];
    #pragma unroll 4
    for (int k = 0; k < 128; ++k)
        s += psum[(size_t)g*128 + k] * inv * fw[(size_t)k*C + cc];
    out[idx] = s;
}

extern "C" void kernel_launch(void* const* d_in, const int* in_sizes, int n_in,
                              void* d_out, int out_size, void* d_ws, size_t ws_size,
                              hipStream_t stream) {
    const float* x       = (const float*)d_in[0];
    const int*   eindex  = (const int*)  d_in[1];
    const int*   etype   = (const int*)  d_in[2];
    const int*   batch   = (const int*)  d_in[4];
    const float* basis   = (const float*)d_in[6];
    const float* comp    = (const float*)d_in[7];
    const float* root    = (const float*)d_in[8];
    const float* bias    = (const float*)d_in[9];
    const float* fc_w    = (const float*)d_in[10];
    const float* fc_b    = (const float*)d_in[11];

    int N  = in_sizes[4];          // 50000
    int E  = in_sizes[2];          // 600000
    int C  = in_sizes[11];         // 16
    int G  = out_size / C;         // 64
    int IO = in_sizes[8];          // 16384
    int B  = in_sizes[6] / IO;     // 4
    int R  = in_sizes[7] / B;      // 8
    int NR = N * R;
    int MB = ceil_div(N, 64);      // 64-row GEMM row-blocks (782)
    int Mpad = MB * 64;
    int grid_gemm = ceil_div(MB, 8) * 16;   // XCD-paired col-split grid (1568)

    const int* src = eindex;
    const int* dst = eindex + E;

    // ---- workspace layout (~121 MB) ----
    char* base = (char*)d_ws;
    size_t off = 0;
    auto alloc = [&](size_t bytes) -> char* {
        char* p = base + off;
        off = align_up(off + bytes, 256);
        return p;
    };
    unsigned short* Bt  = (unsigned short*)alloc(sizeof(unsigned short)*128*1152);
    int*   cnt      = (int*)  alloc(sizeof(int)*(size_t)NR);
    int*   offsets  = (int*)  alloc(sizeof(int)*((size_t)NR+1));
    int*   bsums    = (int*)  alloc(sizeof(int)*1024);
    int*   slot_off = (int*)  alloc(sizeof(int)*((size_t)E+4));
    float* psum     = (float*)alloc(sizeof(float)*(size_t)G*128);
    unsigned short* Xb = (unsigned short*)alloc(sizeof(unsigned short)*(size_t)Mpad*128);
    unsigned short* Mc = (unsigned short*)alloc(sizeof(unsigned short)*(size_t)Mpad*1024);

    // ---- pipeline (9 launches) ----
    pre_kernel<<<1024,256,0,stream>>>(comp, basis, root, Bt, B,
                                      x, (unsigned int*)Xb, N, cnt, NR, psum, G);
    count_kernel<<<ceil_div(E,256),256,0,stream>>>(dst, etype, cnt, E, R);

    int nb = ceil_div(NR, 1024);
    scan_block_kernel<<<nb,256,0,stream>>>(cnt, offsets, bsums, NR);
    scan_block_kernel<<<1,256,0,stream>>>(bsums, bsums, nullptr, nb);
    scan_add_kernel<<<ceil_div(NR,256),256,0,stream>>>(offsets, bsums, NR, E);

    fill_kernel<<<ceil_div(E,256),256,0,stream>>>(src, dst, etype, offsets, slot_off, E, R);

    aggregate_kernel<<<ceil_div(N*4*64,256),256,0,stream>>>(offsets, slot_off,
                                                            (const unsigned int*)Xb,
                                                            (unsigned int*)Mc, N);

    mfma_gemm_kernel<<<grid_gemm,256,0,stream>>>(Mc, Xb, Bt, bias, batch, psum, N, MB);

    fc_kernel<<<ceil_div(G*C,256),256,0,stream>>>(psum, batch, fc_w, fc_b,
                                                  (float*)d_out, N, G, C);
}

// Round 18
// 179.050 us; speedup vs baseline: 1.4603x; 1.0800x over previous
//
#include <hip/hip_runtime.h>

static inline int ceil_div(int a, int b){ return (a+b-1)/b; }
static inline size_t align_up(size_t x, size_t a){ return (x + a - 1) / a * a; }

typedef __bf16 bf16x8 __attribute__((ext_vector_type(8)));
typedef float  f32x4  __attribute__((ext_vector_type(4)));

static __device__ inline unsigned short f2bf(float f){
    unsigned int u = __float_as_uint(f);
    unsigned int lsb = (u >> 16) & 1u;
    u += 0x7FFFu + lsb;
    return (unsigned short)(u >> 16);
}
static __device__ inline float bf2f(unsigned short b){
    return __uint_as_float(((unsigned int)b) << 16);
}
static __device__ inline unsigned int packbf(float a, float b){
    return (unsigned int)f2bf(a) | ((unsigned int)f2bf(b) << 16);
}

// async 16B global->LDS (wave-uniform LDS base + lane*16 layout)
static __device__ inline void gload_lds16(const void* g, void* l) {
    __builtin_amdgcn_global_load_lds(
        (const __attribute__((address_space(1))) unsigned int*)g,
        (__attribute__((address_space(3))) unsigned int*)l, 16, 0, 0);
}

// Merged prologue: zero cnt+psum | build Bt | convert x -> Xb bf16. All independent.
__global__ __launch_bounds__(256)
void pre_kernel(const float* __restrict__ comp, const float* __restrict__ basis,
                const float* __restrict__ root, unsigned short* __restrict__ Bt, int B,
                const float* __restrict__ x, unsigned int* __restrict__ Xb2, int N,
                int* __restrict__ cnt, int NR, float* __restrict__ psum, int G) {
    int gtid = blockIdx.x*blockDim.x + threadIdx.x;
    int gsz  = gridDim.x*blockDim.x;
    for (int i = gtid; i < NR; i += gsz) cnt[i] = 0;
    for (int i = gtid; i < G*128; i += gsz) psum[i] = 0.f;
    for (int idx = gtid; idx < 128*1152; idx += gsz) {
        int o = idx / 1152, kk = idx - o*1152;
        float val;
        if (kk < 1024) {
            int r = kk >> 7, i = kk & 127;
            val = 0.f;
            for (int b = 0; b < B; ++b)
                val += comp[r*B+b] * basis[((size_t)b*128 + i)*128 + o];
        } else {
            val = root[(size_t)(kk-1024)*128 + o];
        }
        Bt[idx] = f2bf(val);
    }
    for (int tt = gtid; tt < N*64; tt += gsz) {
        int n = tt >> 6, l = tt & 63;
        float2 v = reinterpret_cast<const float2*>(x + (size_t)n*128)[l];
        Xb2[(size_t)n*64 + l] = packbf(v.x, v.y);
    }
}

__global__ void count_kernel(const int* __restrict__ dst, const int* __restrict__ et,
                             int* __restrict__ cnt, int E, int R) {
    int e = blockIdx.x*blockDim.x + threadIdx.x;
    if (e >= E) return;
    atomicAdd(&cnt[(size_t)dst[e]*R + et[e]], 1);
}

__global__ __launch_bounds__(256)
void scan_block_kernel(const int* __restrict__ in, int* __restrict__ out,
                       int* __restrict__ bsums, int n) {
    __shared__ int tsum[256];
    int t = threadIdx.x;
    int idx0 = blockIdx.x*1024 + t*4;
    int v0 = (idx0+0 < n) ? in[idx0+0] : 0;
    int v1 = (idx0+1 < n) ? in[idx0+1] : 0;
    int v2 = (idx0+2 < n) ? in[idx0+2] : 0;
    int v3 = (idx0+3 < n) ? in[idx0+3] : 0;
    int s = v0+v1+v2+v3;
    tsum[t] = s; __syncthreads();
    for (int off = 1; off < 256; off <<= 1) {
        int x = (t >= off) ? tsum[t-off] : 0;
        __syncthreads();
        tsum[t] += x;
        __syncthreads();
    }
    int run = tsum[t] - s;
    if (idx0+0 < n) out[idx0+0] = run; run += v0;
    if (idx0+1 < n) out[idx0+1] = run; run += v1;
    if (idx0+2 < n) out[idx0+2] = run; run += v2;
    if (idx0+3 < n) out[idx0+3] = run;
    if (bsums && t == 255) bsums[blockIdx.x] = tsum[255];
}

__global__ void scan_add_kernel(int* __restrict__ out, const int* __restrict__ bs,
                                int n, int total) {
    int i = blockIdx.x*blockDim.x + threadIdx.x;
    if (i < n) out[i] += bs[i >> 10];
    if (i == 0) out[n] = total;
}

// slot = atomicAdd(&offsets[bin],1): offsets mutates into shifted-by-one bounds.
// slot_off stores PRE-SHIFTED u32 index (src<<6). Pad of 4 zeros after E.
__global__ void fill_kernel(const int* __restrict__ src, const int* __restrict__ dst,
                            const int* __restrict__ et, int* __restrict__ offsets,
                            int* __restrict__ slot_off, int E, int R) {
    int e = blockIdx.x*blockDim.x + threadIdx.x;
    if (e >= E) return;
    if (e < 4) slot_off[E + e] = 0;
    int bin = dst[e]*R + et[e];
    int slot = atomicAdd(&offsets[bin], 1);
    slot_off[slot] = src[e] << 6;
}

// 4 waves per node, 2 bins per wave. Bounds shifted-by-one: bin b = [off[b-1], off[b]).
// Masked always-4-wide gather, unclamped (slot_off padded). PLAIN stores (no nt):
// Mc (102 MB) fits L3 -> GEMM re-reads hit L3 instead of HBM.
__global__ __launch_bounds__(256)
void aggregate_kernel(const int* __restrict__ offsets, const int* __restrict__ slot_off,
                      const unsigned int* __restrict__ Xb2, unsigned int* __restrict__ Mc2,
                      int N) {
    int gw = (int)((blockIdx.x*blockDim.x + threadIdx.x) >> 6);
    int node = gw >> 2, part = gw & 3;
    if (node >= N) return;
    int l = threadIdx.x & 63;
    int base = node*8 + part*2;
    int lo   = (base == 0) ? 0 : offsets[base-1];
    int bmid = offsets[base];
    int hi   = offsets[base+1];

    float ax0=0.f, ay0=0.f, ax1=0.f, ay1=0.f;

#define ACC2(E_, U_) { \
    float vx_ = bf2f((unsigned short)((U_) & 0xFFFFu)); \
    float vy_ = bf2f((unsigned short)((U_) >> 16)); \
    if ((E_) < bmid) { ax0 += vx_; ay0 += vy_; } \
    else             { ax1 += vx_; ay1 += vy_; } }

    for (int e = lo; e < hi; e += 4) {
        int s0 = slot_off[e];
        int s1 = slot_off[e+1];
        int s2 = slot_off[e+2];
        int s3 = slot_off[e+3];
        unsigned int u0 = Xb2[(unsigned)(s0 + l)];
        unsigned int u1 = Xb2[(unsigned)(s1 + l)];
        unsigned int u2 = Xb2[(unsigned)(s2 + l)];
        unsigned int u3 = Xb2[(unsigned)(s3 + l)];
        if (e+1 >= hi) u1 = 0u;        // wave-uniform masks
        if (e+2 >= hi) u2 = 0u;
        if (e+3 >= hi) u3 = 0u;
        ACC2(e+0, u0) ACC2(e+1, u1) ACC2(e+2, u2) ACC2(e+3, u3)
    }
#undef ACC2

    unsigned int* Mrow = Mc2 + (size_t)node*512;
    float i0 = 1.f/fmaxf((float)(bmid-lo), 1.f);
    float i1 = 1.f/fmaxf((float)(hi-bmid), 1.f);
    Mrow[(2*part+0)*64 + l] = packbf(ax0*i0, ay0*i0);
    Mrow[(2*part+1)*64 + l] = packbf(ax1*i1, ay1*i1);
}

// GEMM + fused pooling epilogue (R17-proven). NO h buffer:
// psum[g][col] += sum over rows of graph g of relu([Mc|Xb] @ Bt^T + bias).
__global__ __launch_bounds__(256)
void mfma_gemm_kernel(const unsigned short* __restrict__ Mc,
                      const unsigned short* __restrict__ Xb,
                      const unsigned short* __restrict__ Btc,
                      const float* __restrict__ bias,
                      const int* __restrict__ batch,
                      float* __restrict__ psum, int Nrows, int MBrows) {
    __shared__ char ldsRaw[32768];   // [0,16K): A bufs 0/1; [16K,32K): B bufs 0/1
    auto ldsA = [&](int buf) -> char* { return ldsRaw + buf*8192; };
    auto ldsB = [&](int buf) -> char* { return ldsRaw + 16384 + buf*8192; };

    int tid  = threadIdx.x;
    int lane = tid & 63;
    int wid  = tid >> 6;
    int rg = wid & 1, cg = wid >> 1;
    int fr = lane & 15, kb = lane >> 4;

    int blk = blockIdx.x;
    int q = blk >> 4, rem = blk & 15, c = rem >> 3, m = rem & 7;
    int rb = q*8 + m;
    if (rb >= MBrows) return;
    long m0 = (long)rb * 64;
    int colbase = c * 64;

    int lrow8 = lane >> 3;            // 0..7 row within a gload issue
    int lcb   = (lane & 7) * 16;      // 16B slot within 128B row

    f32x4 acc[2][2];
    #pragma unroll
    for (int mf = 0; mf < 2; ++mf)
        #pragma unroll
        for (int nf = 0; nf < 2; ++nf) acc[mf][nf] = f32x4{0.f,0.f,0.f,0.f};

    const char* McB = (const char*)Mc;
    const char* XbB = (const char*)Xb;
    const char* BtB = (const char*)Btc;

    for (int t = 0; t < 18; ++t) {
        int cur = t & 1;
        #pragma unroll
        for (int i = 0; i < 2; ++i) {
            int row = wid*16 + i*8 + lrow8;
            int sw  = lcb ^ ((row & 7) << 4);
            const char* g = (t < 16)
                ? McB + (size_t)(m0 + row)*2048 + t*128 + sw
                : XbB + (size_t)(m0 + row)*256 + (t-16)*128 + sw;
            gload_lds16(g, ldsA(cur) + wid*2048 + i*1024 + lane*16);
        }
        #pragma unroll
        for (int i = 0; i < 2; ++i) {
            int col = wid*16 + i*8 + lrow8;       // local col 0..63
            int sw  = lcb ^ ((col & 7) << 4);
            const char* g = BtB + (size_t)(colbase + col)*2304 + t*128 + sw;
            gload_lds16(g, ldsB(cur) + wid*2048 + i*1024 + lane*16);
        }
        __syncthreads();

        bf16x8 af[2][2], bfr[2][2];
        #pragma unroll
        for (int mf = 0; mf < 2; ++mf) {
            int row = rg*32 + mf*16 + fr;
            #pragma unroll
            for (int kk = 0; kk < 2; ++kk) {
                int byte = row*128 + ((kk*64 + kb*16) ^ ((row & 7) << 4));
                af[mf][kk] = *reinterpret_cast<const bf16x8*>(ldsA(cur) + byte);
            }
        }
        #pragma unroll
        for (int nf = 0; nf < 2; ++nf) {
            int col = cg*32 + nf*16 + fr;         // local col
            #pragma unroll
            for (int kk = 0; kk < 2; ++kk) {
                int byte = col*128 + ((kk*64 + kb*16) ^ ((col & 7) << 4));
                bfr[nf][kk] = *reinterpret_cast<const bf16x8*>(ldsB(cur) + byte);
            }
        }
        #pragma unroll
        for (int kk = 0; kk < 2; ++kk)
            #pragma unroll
            for (int mf = 0; mf < 2; ++mf)
                #pragma unroll
                for (int nf = 0; nf < 2; ++nf)
                    acc[mf][nf] = __builtin_amdgcn_mfma_f32_16x16x32_bf16(
                        af[mf][kk], bfr[nf][kk], acc[mf][nf], 0, 0, 0);
        __syncthreads();
    }

    // ---- fused pooling epilogue ----
    float bb[2];
    #pragma unroll
    for (int nf = 0; nf < 2; ++nf) bb[nf] = bias[colbase + cg*32 + nf*16 + fr];

    float* ldsF = (float*)ldsRaw;     // [64][66] f32 = 16896 B (staging LDS is dead)
    #pragma unroll
    for (int mf = 0; mf < 2; ++mf)
        #pragma unroll
        for (int q2 = 0; q2 < 4; ++q2) {
            int rl = rg*32 + mf*16 + kb*4 + q2;
            #pragma unroll
            for (int nf = 0; nf < 2; ++nf) {
                int cl = cg*32 + nf*16 + fr;
                ldsF[rl*66 + cl] = fmaxf(acc[mf][nf][q2] + bb[nf], 0.f);
            }
        }
    __syncthreads();

    int col = tid & 63, rq = tid >> 6;      // 4 threads per column, 16 rows each
    float partial = 0.f;
    int gcur = -1;
    for (int i = 0; i < 16; ++i) {
        long row = m0 + rq*16 + i;
        if (row >= Nrows) break;
        int g = batch[row];
        if (g != gcur) {
            if (gcur >= 0) atomicAdd(&psum[(size_t)gcur*128 + colbase + col], partial);
            gcur = g; partial = 0.f;
        }
        partial += ldsF[(rq*16 + i)*66 + col];
    }
    if (gcur >= 0) atomicAdd(&psum[(size_t)gcur*128 + colbase + col], partial);
}

// out[g][c] = (psum[g]/cnt_g) @ fc_w + fc_b   (G*C threads; cnt via binary search)
__global__ void fc_kernel(const float* __restrict__ psum, const int* __restrict__ batch,
                          const float* __restrict__ fw, const float* __restrict__ fb,
                          float* __restrict__ out, int N, int G, int C) {
    int idx = blockIdx.x*blockDim.x + threadIdx.x;
    if (idx >= G*C) return;
    int g = idx / C, cc = idx - g*C;
    int lo = 0, hi = N;
    while (lo < hi) { int mid = (lo+hi) >> 1; if (batch[mid] < g) lo = mid+1; else hi = mid; }
    int s0 = lo;
    hi = N;
    while (lo < hi) { int mid = (lo+hi) >> 1; if (batch[mid] < g+1) lo = mid+1; else hi = mid; }
    float inv = 1.f / fmaxf((float)(lo - s0), 1.f);
    float s = fb[cc];
    #pragma unroll 4
    for (int k = 0; k < 128; ++k)
        s += psum[(size_t)g*128 + k] * inv * fw[(size_t)k*C + cc];
    out[idx] = s;
}

extern "C" void kernel_launch(void* const* d_in, const int* in_sizes, int n_in,
                              void* d_out, int out_size, void* d_ws, size_t ws_size,
                              hipStream_t stream) {
    const float* x       = (const float*)d_in[0];
    const int*   eindex  = (const int*)  d_in[1];
    const int*   etype   = (const int*)  d_in[2];
    const int*   batch   = (const int*)  d_in[4];
    const float* basis   = (const float*)d_in[6];
    const float* comp    = (const float*)d_in[7];
    const float* root    = (const float*)d_in[8];
    const float* bias    = (const float*)d_in[9];
    const float* fc_w    = (const float*)d_in[10];
    const float* fc_b    = (const float*)d_in[11];

    int N  = in_sizes[4];          // 50000
    int E  = in_sizes[2];          // 600000
    int C  = in_sizes[11];         // 16
    int G  = out_size / C;         // 64
    int IO = in_sizes[8];          // 16384
    int B  = in_sizes[6] / IO;     // 4
    int R  = in_sizes[7] / B;      // 8
    int NR = N * R;
    int MB = ceil_div(N, 64);      // 64-row GEMM row-blocks (782)
    int Mpad = MB * 64;
    int grid_gemm = ceil_div(MB, 8) * 16;   // XCD-paired col-split grid (1568)

    const int* src = eindex;
    const int* dst = eindex + E;

    // ---- workspace layout (~121 MB) ----
    char* base = (char*)d_ws;
    size_t off = 0;
    auto alloc = [&](size_t bytes) -> char* {
        char* p = base + off;
        off = align_up(off + bytes, 256);
        return p;
    };
    unsigned short* Bt  = (unsigned short*)alloc(sizeof(unsigned short)*128*1152);
    int*   cnt      = (int*)  alloc(sizeof(int)*(size_t)NR);
    int*   offsets  = (int*)  alloc(sizeof(int)*((size_t)NR+1));
    int*   bsums    = (int*)  alloc(sizeof(int)*1024);
    int*   slot_off = (int*)  alloc(sizeof(int)*((size_t)E+4));
    float* psum     = (float*)alloc(sizeof(float)*(size_t)G*128);
    unsigned short* Xb = (unsigned short*)alloc(sizeof(unsigned short)*(size_t)Mpad*128);
    unsigned short* Mc = (unsigned short*)alloc(sizeof(unsigned short)*(size_t)Mpad*1024);

    // ---- pipeline (9 launches) ----
    pre_kernel<<<1024,256,0,stream>>>(comp, basis, root, Bt, B,
                                      x, (unsigned int*)Xb, N, cnt, NR, psum, G);
    count_kernel<<<ceil_div(E,256),256,0,stream>>>(dst, etype, cnt, E, R);

    int nb = ceil_div(NR, 1024);
    scan_block_kernel<<<nb,256,0,stream>>>(cnt, offsets, bsums, NR);
    scan_block_kernel<<<1,256,0,stream>>>(bsums, bsums, nullptr, nb);
    scan_add_kernel<<<ceil_div(NR,256),256,0,stream>>>(offsets, bsums, NR, E);

    fill_kernel<<<ceil_div(E,256),256,0,stream>>>(src, dst, etype, offsets, slot_off, E, R);

    aggregate_kernel<<<ceil_div(N*4*64,256),256,0,stream>>>(offsets, slot_off,
                                                            (const unsigned int*)Xb,
                                                            (unsigned int*)Mc, N);

    mfma_gemm_kernel<<<grid_gemm,256,0,stream>>>(Mc, Xb, Bt, bias, batch, psum, N, MB);

    fc_kernel<<<ceil_div(G*C,256),256,0,stream>>>(psum, batch, fc_w, fc_b,
                                                  (float*)d_out, N, G, C);
}